// Round 2
// baseline (610.968 us; speedup 1.0000x reference)
//
#include <hip/hip_runtime.h>

// ---------------------------------------------------------------------------
// SkilledLoRA: out[b,t,o] = sum_i x[b,t,i]*W[o,i] + bias[o]
//                         + 2.0 * sum_r (sum_i x[b,t,i]*A[b,i,r]) * B[b,r,o]
// Round 2 design: plain bf16-RNE MFMA for the base GEMM (threshold 0.11875
// tolerates bf16; predicted absmax ~0.01), adapter in fp32 VALU epilogue.
// ws usage 11 MB. No swizzled-source global_load_lds, no augmented layouts.
// ---------------------------------------------------------------------------

typedef __attribute__((ext_vector_type(8))) short short8;
typedef __attribute__((ext_vector_type(4))) float f32x4;

#define INF   2048
#define OUTF  2048
#define RANK  16
#define BM    128
#define BN    128
#define BK    32

// round-to-nearest-even f32 -> bf16 (bit trick; inputs are normal finite data)
__device__ __forceinline__ unsigned short bf16rne(float f) {
    unsigned int u = __float_as_uint(f);
    unsigned int r = u + 0x7FFFu + ((u >> 16) & 1u);
    return (unsigned short)(r >> 16);
}

__device__ __forceinline__ void gload_lds16(const void* g, void* l) {
    __builtin_amdgcn_global_load_lds(
        (const __attribute__((address_space(1))) unsigned int*)g,
        (__attribute__((address_space(3))) unsigned int*)l, 16, 0, 0);
}

// ---------------------------------------------------------------------------
// K1: W [2048][2048] f32 -> bf16 (RNE)
// ---------------------------------------------------------------------------
__global__ __launch_bounds__(256) void k_wbf16(const float4* __restrict__ W,
                                               ushort4* __restrict__ o) {
    int g = blockIdx.x * 256 + threadIdx.x;   // 1,048,576 float4s, grid 4096
    float4 f = W[g];
    o[g] = make_ushort4(bf16rne(f.x), bf16rne(f.y), bf16rne(f.z), bf16rne(f.w));
}

// ---------------------------------------------------------------------------
// K2: skill mixing (fp32, exact)
//   Amix[b][i][r] =       sum_s w[b,q(i),s] * lora_a[q][s][d(i)][r]
//   Bmix[b][r][o] = 2.0 * sum_s w[b,q(o),s] * lora_b[q][s][r][d(o)]
// ---------------------------------------------------------------------------
__global__ __launch_bounds__(256) void k_mix(const float* __restrict__ wts,
                                             const float* __restrict__ la,
                                             const float* __restrict__ lb,
                                             float* __restrict__ Amix,
                                             float* __restrict__ Bmix) {
    int gid = blockIdx.x * 256 + threadIdx.x;   // 16384 = 8 * 2048, grid 64
    int b = gid >> 11, i = gid & 2047;
    int q = i >> 9, d = i & 511;
    float w[8];
#pragma unroll
    for (int s = 0; s < 8; ++s) w[s] = wts[(b * 4 + q) * 8 + s];

    float accA[16];
#pragma unroll
    for (int r = 0; r < 16; ++r) accA[r] = 0.f;
#pragma unroll
    for (int s = 0; s < 8; ++s) {
        const float4* pa = (const float4*)(la + (((q * 8 + s) * 512 + d) << 4));
        float4 a0 = pa[0], a1 = pa[1], a2 = pa[2], a3 = pa[3];
        float wv = w[s];
        accA[0]  += wv * a0.x; accA[1]  += wv * a0.y; accA[2]  += wv * a0.z; accA[3]  += wv * a0.w;
        accA[4]  += wv * a1.x; accA[5]  += wv * a1.y; accA[6]  += wv * a1.z; accA[7]  += wv * a1.w;
        accA[8]  += wv * a2.x; accA[9]  += wv * a2.y; accA[10] += wv * a2.z; accA[11] += wv * a2.w;
        accA[12] += wv * a3.x; accA[13] += wv * a3.y; accA[14] += wv * a3.z; accA[15] += wv * a3.w;
    }
    float4* pA = (float4*)(Amix + ((size_t)gid << 4));
    pA[0] = make_float4(accA[0],  accA[1],  accA[2],  accA[3]);
    pA[1] = make_float4(accA[4],  accA[5],  accA[6],  accA[7]);
    pA[2] = make_float4(accA[8],  accA[9],  accA[10], accA[11]);
    pA[3] = make_float4(accA[12], accA[13], accA[14], accA[15]);

    float accB[16];
#pragma unroll
    for (int r = 0; r < 16; ++r) accB[r] = 0.f;
#pragma unroll
    for (int s = 0; s < 8; ++s) {
        float wv = w[s];
#pragma unroll
        for (int r = 0; r < 16; ++r)
            accB[r] += wv * lb[((q * 8 + s) * 16 + r) * 512 + d];
    }
#pragma unroll
    for (int r = 0; r < 16; ++r)
        Bmix[((size_t)(b * 16 + r) << 11) + i] = 2.0f * accB[r];   // coalesced per r
}

// ---------------------------------------------------------------------------
// K3: T[row][r] = sum_k x[row][k] * Amix[b][k][r]   (fp32)
// one wave per row; 64-lane butterfly reduce
// ---------------------------------------------------------------------------
__global__ __launch_bounds__(256) void k_xa(const float* __restrict__ x,
                                            const float* __restrict__ Amix,
                                            float* __restrict__ T) {
    int row = blockIdx.x * 4 + (threadIdx.x >> 6);   // grid 4096
    int lane = threadIdx.x & 63;
    int b = row >> 11;
    const float* xr = x + (size_t)row * INF;
    const float4* A4 = (const float4*)(Amix + ((size_t)b << 15));  // [2048][16]

    float acc[16];
#pragma unroll
    for (int r = 0; r < 16; ++r) acc[r] = 0.f;
    for (int k = lane; k < INF; k += 64) {
        float xv = xr[k];
        float4 a0 = A4[k * 4 + 0], a1 = A4[k * 4 + 1], a2 = A4[k * 4 + 2], a3 = A4[k * 4 + 3];
        acc[0]  += xv * a0.x; acc[1]  += xv * a0.y; acc[2]  += xv * a0.z; acc[3]  += xv * a0.w;
        acc[4]  += xv * a1.x; acc[5]  += xv * a1.y; acc[6]  += xv * a1.z; acc[7]  += xv * a1.w;
        acc[8]  += xv * a2.x; acc[9]  += xv * a2.y; acc[10] += xv * a2.z; acc[11] += xv * a2.w;
        acc[12] += xv * a3.x; acc[13] += xv * a3.y; acc[14] += xv * a3.z; acc[15] += xv * a3.w;
    }
#pragma unroll
    for (int off = 1; off < 64; off <<= 1) {
#pragma unroll
        for (int r = 0; r < 16; ++r) acc[r] += __shfl_xor(acc[r], off);
    }
    // static-index select of acc[lane] for lane<16 (rule #20: no runtime index)
    int r = lane & 15;
    float a0 = (r & 1) ? acc[1]  : acc[0];
    float a1 = (r & 1) ? acc[3]  : acc[2];
    float a2 = (r & 1) ? acc[5]  : acc[4];
    float a3 = (r & 1) ? acc[7]  : acc[6];
    float a4 = (r & 1) ? acc[9]  : acc[8];
    float a5 = (r & 1) ? acc[11] : acc[10];
    float a6 = (r & 1) ? acc[13] : acc[12];
    float a7 = (r & 1) ? acc[15] : acc[14];
    float b0 = (r & 2) ? a1 : a0;
    float b1 = (r & 2) ? a3 : a2;
    float b2 = (r & 2) ? a5 : a4;
    float b3 = (r & 2) ? a7 : a6;
    float c0 = (r & 4) ? b1 : b0;
    float c1 = (r & 4) ? b3 : b2;
    float v  = (r & 8) ? c1 : c0;
    if (lane < 16) T[((size_t)row << 4) + lane] = v;
}

// ---------------------------------------------------------------------------
// K4: base GEMM (bf16 MFMA) + fp32 adapter epilogue + bias.
// 128x128 tile, BK=32, 4 waves (2x2), 16 MFMA per K-step per wave.
// W staged via linear global_load_lds (bf16, pre-converted); x reg-staged
// f32 -> bf16 RNE -> ds_write. Adapter: rank-16 fp32 dot from LDS tiles.
// ---------------------------------------------------------------------------
__global__ __launch_bounds__(256)
void k_gemm(const float* __restrict__ x,
            const unsigned short* __restrict__ Wbf,
            const float* __restrict__ bias,
            const float* __restrict__ T,
            const float* __restrict__ Bmix,
            float* __restrict__ out) {
    __shared__ __align__(16) char smem[16384];
    unsigned short* ldsA = (unsigned short*)smem;            // [128][32] bf16 (x)
    unsigned short* ldsB = (unsigned short*)(smem + 8192);   // [128][32] bf16 (W)

    const int tid = threadIdx.x;
    const int wid = tid >> 6;
    const int lane = tid & 63;

    // XCD-aware swizzle (2048 blocks, 2048 % 8 == 0 -> bijective)
    int swz = ((blockIdx.x & 7) << 8) | (blockIdx.x >> 3);
    const int m0 = (swz >> 4) << 7;   // 128 M-tiles (each XCD owns one m-range)
    const int n0 = (swz & 15) << 7;   // 16  N-tiles
    const int b  = m0 >> 11;          // batch (128 | 2048)

    const int wm = (wid >> 1) << 6;
    const int wn = (wid & 1) << 6;

    f32x4 acc[4][4];
#pragma unroll
    for (int i = 0; i < 4; ++i)
#pragma unroll
        for (int j = 0; j < 4; ++j) acc[i][j] = (f32x4){0.f, 0.f, 0.f, 0.f};

    const int ar = tid >> 3;            // x-staging: rows (ar + 32j)
    const int ac = (tid & 7) << 2;      // f32 col group
    const float* xbase = x + (size_t)(m0 + ar) * INF + ac;

    for (int kt = 0; kt < 64; ++kt) {
        const int k0 = kt << 5;
        __syncthreads();   // previous iteration's readers done

        // W-tile: async global->LDS, linear [128][32] bf16; 2 gloads/wave
#pragma unroll
        for (int c = 0; c < 2; ++c) {
            int rr = (wid << 5) + (c << 4);            // 16 rows per 1KB gload
            int srow = n0 + rr + (lane >> 2);
            int scol = k0 + ((lane & 3) << 3);
            gload_lds16(Wbf + (size_t)srow * INF + scol, &ldsB[rr * BK]);
        }
        // x-tile: f32 load -> bf16 RNE -> contiguous b64 LDS writes
#pragma unroll
        for (int j = 0; j < 4; ++j) {
            float4 f = *(const float4*)(xbase + (size_t)(j * 32) * INF + k0);
            int rw = (ar + j * 32) * BK + ac;
            *(ushort4*)&ldsA[rw] =
                make_ushort4(bf16rne(f.x), bf16rne(f.y), bf16rne(f.z), bf16rne(f.w));
        }
        __syncthreads();   // drains vmcnt (gload_lds) + lgkmcnt (ds_write)

        short8 av[4], bv[4];
        const int fr = lane & 15;
        const int fs = (lane >> 4) << 3;
#pragma unroll
        for (int mf = 0; mf < 4; ++mf)
            av[mf] = *(const short8*)&ldsA[(wm + mf * 16 + fr) * BK + fs];
#pragma unroll
        for (int nf = 0; nf < 4; ++nf)
            bv[nf] = *(const short8*)&ldsB[(wn + nf * 16 + fr) * BK + fs];
#pragma unroll
        for (int mf = 0; mf < 4; ++mf)
#pragma unroll
            for (int nf = 0; nf < 4; ++nf)
                acc[mf][nf] = __builtin_amdgcn_mfma_f32_16x16x32_bf16(av[mf], bv[nf], acc[mf][nf], 0, 0, 0);
    }

    // ---- epilogue: fp32 adapter (rank-16) + bias ----
    __syncthreads();                                   // K-loop readers done
    float* ldsT  = (float*)smem;                       // [16][128]  T^t tile
    float* ldsB2 = (float*)(smem + 8192);              // [16][128]  Bmix tile
    {
        // stage T transposed: ldsT[r][row] = T[m0+row][r]
        int row = tid >> 1, half = tid & 1;
        const float* Tp = T + (((size_t)(m0 + row)) << 4) + half * 8;
        float4 v0 = *(const float4*)Tp;
        float4 v1 = *(const float4*)(Tp + 4);
        int rb = half * 8;
        ldsT[(rb + 0) * 128 + row] = v0.x;
        ldsT[(rb + 1) * 128 + row] = v0.y;
        ldsT[(rb + 2) * 128 + row] = v0.z;
        ldsT[(rb + 3) * 128 + row] = v0.w;
        ldsT[(rb + 4) * 128 + row] = v1.x;
        ldsT[(rb + 5) * 128 + row] = v1.y;
        ldsT[(rb + 6) * 128 + row] = v1.z;
        ldsT[(rb + 7) * 128 + row] = v1.w;
        // stage Bmix: ldsB2[r][col] = Bmix[b][r][n0+col]
        int r = tid >> 4, c8 = (tid & 15) << 3;
        const float* Bp = Bmix + ((size_t)(b * 16 + r) << 11) + n0 + c8;
        float4 u0 = *(const float4*)Bp;
        float4 u1 = *(const float4*)(Bp + 4);
        *(float4*)&ldsB2[r * 128 + c8]     = u0;
        *(float4*)&ldsB2[r * 128 + c8 + 4] = u1;
    }
    __syncthreads();

    const int fr = lane & 15;
    const int fq = lane >> 4;
#pragma unroll
    for (int r = 0; r < 16; ++r) {
        f32x4 tv[4];
#pragma unroll
        for (int mf = 0; mf < 4; ++mf)
            tv[mf] = *(const f32x4*)&ldsT[r * 128 + wm + mf * 16 + (fq << 2)];
        float bw[4];
#pragma unroll
        for (int nf = 0; nf < 4; ++nf)
            bw[nf] = ldsB2[r * 128 + wn + nf * 16 + fr];
#pragma unroll
        for (int mf = 0; mf < 4; ++mf)
#pragma unroll
            for (int nf = 0; nf < 4; ++nf)
                acc[mf][nf] += tv[mf] * bw[nf];
    }

#pragma unroll
    for (int nf = 0; nf < 4; ++nf) {
        int col = n0 + wn + nf * 16 + fr;
        float bv = bias[col];
#pragma unroll
        for (int mf = 0; mf < 4; ++mf) {
            int rbase = m0 + wm + mf * 16 + (fq << 2);
#pragma unroll
            for (int j = 0; j < 4; ++j)
                out[(size_t)(rbase + j) * OUTF + col] = acc[mf][nf][j] + bv;
        }
    }
}

// ---------------------------------------------------------------------------
extern "C" void kernel_launch(void* const* d_in, const int* in_sizes, int n_in,
                              void* d_out, int out_size, void* d_ws, size_t ws_size,
                              hipStream_t stream) {
    const float* x      = (const float*)d_in[0];
    const float* wts    = (const float*)d_in[1];
    const float* W      = (const float*)d_in[2];
    const float* bias   = (const float*)d_in[3];
    const float* lora_a = (const float*)d_in[4];
    const float* lora_b = (const float*)d_in[5];
    float* out = (float*)d_out;

    char* ws = (char*)d_ws;                                      // 11 MB used
    unsigned short* Wbf  = (unsigned short*)(ws);                // 8 MB
    float*          Amix = (float*)(ws + (8u  << 20));           // 1 MB [8][2048][16]
    float*          Bmix = (float*)(ws + (9u  << 20));           // 1 MB [8][16][2048]
    float*          Tm   = (float*)(ws + (10u << 20));           // 1 MB [16384][16]

    k_wbf16<<<4096, 256, 0, stream>>>((const float4*)W, (ushort4*)Wbf);
    k_mix  <<<64,   256, 0, stream>>>(wts, lora_a, lora_b, Amix, Bmix);
    k_xa   <<<4096, 256, 0, stream>>>(x, Amix, Tm);
    k_gemm <<<2048, 256, 0, stream>>>(x, Wbf, bias, Tm, Bmix, out);
}